// Round 3
// baseline (460.950 us; speedup 1.0000x reference)
//
#include <hip/hip_runtime.h>

#define NL 16384          // row length
#define NB 64             // rows = blocks
#define NT 1024           // threads per block (16 waves = 4 waves/SIMD)
#define NC (NL / NT)      // 16 elements per thread == bits in the peak mask
#define NW (NT / 64)      // 16 waves
#define N_ITER 12
#define N_IMFS 6

#pragma clang fp contract(off)   // everything unfused EXCEPT the explicit fmaf

#define HSZ (NL + (NL >> 5))   // +1 float per 32: 2-way-max banking (free)
__device__ __forceinline__ int physi(int i) { return i + (i >> 5); }

#define FMAXV 3.402823466e38f

// Frozen bit-exact semantics (certified R9/R11/R13, absmax 0.0).
// R12: NT 512->1024 (occupancy 6->12%), 283->251us; VALUBusy flat -> DS-pipe
// throughput-bound, not latency-bound.
// R13 (DS diet): h in VGPRs across A->C->subtract, meanb eliminated, 4 of 7
// prefix scans -> ballot+1 shfl, Mx/Mn scans behind rare uniform branch.
// R13 FAILED at 404us: halving LDS to 69KB let hipcc target 2 blocks/CU
// (8 waves/EU) -> VGPR capped at 64 -> hr/mr/rv spilled (FETCH 7.5->33MB,
// WRITE 50->203MB of scratch). Grid is 64 blocks on 256 CUs, so 2 blocks/CU
// is unreachable anyway.
// R14: pin amdgpu_waves_per_eu(4,4) -> 128-VGPR budget, arrays stay in regs.
__global__ __attribute__((amdgpu_flat_work_group_size(NT, NT),
                          amdgpu_waves_per_eu(4, 4)))
void emd_main(
    const float* __restrict__ x, float* __restrict__ out,
    unsigned* cnt, double* sdsl, double* flsl) {
  __shared__ float h[HSZ];        // 67584 B (only big LDS buffer now)
  __shared__ int wLU[NW], wLL[NW], wNU[NW], wNL[NW];
  __shared__ float wMx[NW], wMn[NW];
  __shared__ unsigned wCT[NW];
  __shared__ int eLU[NW], eLL[NW], eNU[NW], eNL[NW];
  __shared__ float eMx[NW], eMn[NW];
  __shared__ unsigned sTot;
  __shared__ double tA[NW], tB[NW], tC[NW], tD[NW];
  __shared__ int sFlag;

  const int t = threadIdx.x;
  const int lane = t & 63;
  const int wv = t >> 6;
  const int row = blockIdx.x;
  const int base = t * NC;
  const float* xr = x + (size_t)row * NL;
  float* res = out + (size_t)N_IMFS * NB * NL + (size_t)row * NL;

  float hr[NC];   // register-resident h (always == LDS h after each barrier)

  // init: h = x row (regs + LDS, swizzled); res slab of d_out = x
  #pragma unroll
  for (int q = 0; q < NC / 4; q++) {
    int i0 = base + q * 4;
    float4 v = *(const float4*)&xr[i0];
    hr[q * 4 + 0] = v.x; hr[q * 4 + 1] = v.y;
    hr[q * 4 + 2] = v.z; hr[q * 4 + 3] = v.w;
    *(float4*)&h[physi(i0)] = v;
    *(float4*)&res[i0] = v;
  }
  __syncthreads();

  unsigned ep = 0;
  bool done = false;

  for (int k = 0; k < N_IMFS; k++) {
    float* outk = out + (size_t)k * NB * NL + (size_t)row * NL;
    if (done) {  // globally-uniform skip (no barriers)
      #pragma unroll
      for (int q = 0; q < NC / 4; q++)
        *(float4*)&outk[base + q * 4] = make_float4(0.f, 0.f, 0.f, 0.f);
      continue;
    }

    // ---------------- sifting ----------------
    for (int it = 0; it < N_ITER; it++) {
      // pass A: rolling walk over registers -> peak masks + chunk summaries
      unsigned mU = 0, mL = 0;
      int lmU = -1, lmL = -1, cU = 0, cL = 0;
      float rmx = -FMAXV, rmn = FMAXV;
      {
        float hm = (base > 0) ? h[physi(base - 1)] : 0.0f;   // neighbor (LDS)
        #pragma unroll
        for (int j = 0; j < NC; j++) {
          int i = base + j;
          float hc = hr[j];
          float hp = (j + 1 < NC) ? hr[j + 1]
                                  : ((i + 1 < NL) ? h[physi(i + 1)] : 0.0f);
          bool in = (i > 0) && (i + 1 < NL);
          if (in && hm < hc && hc > hp) { mU |= (1u << j); lmU = i; cU++; }
          if (in && hm > hc && hc < hp) { mL |= (1u << j); lmL = i; cL++; }
          rmx = fmaxf(rmx, hc);
          rmn = fminf(rmn, hc);
          hm = hc;
        }
      }
      int fpU = mU ? (base + __ffs(mU) - 1) : NL;   // first own peak
      int fpL = mL ? (base + __ffs(mL) - 1) : NL;
      unsigned long long bUm = __ballot(mU != 0);
      unsigned long long bLm = __ballot(mL != 0);
      // wave summaries: owning lane stores directly (no scans)
      {
        int s;
        s = bUm ? (63 - __clzll((long long)bUm)) : 0;
        if (lane == s) wLU[wv] = bUm ? lmU : -1;
        s = bLm ? (63 - __clzll((long long)bLm)) : 0;
        if (lane == s) wLL[wv] = bLm ? lmL : -1;
        s = bUm ? (__ffsll(bUm) - 1) : 0;
        if (lane == s) wNU[wv] = bUm ? fpU : NL;
        s = bLm ? (__ffsll(bLm) - 1) : 0;
        if (lane == s) wNL[wv] = bLm ? fpL : NL;
      }
      // block peak-count totals (reduce only; same pairwise order as before)
      unsigned ict = ((unsigned)cU << 16) | (unsigned)cL;
      #pragma unroll
      for (int o = 1; o < 64; o <<= 1) {
        unsigned cc = __shfl_down(ict, o, 64);
        if (lane + o < 64) ict += cc;
      }
      if (lane == 0) wCT[wv] = ict;
      __syncthreads();
      if (t == 0) {  // 16-entry serial combine -> exclusive wave carries
        int aLU = -1, aLL = -1; unsigned tt = 0;
        for (int w = 0; w < NW; w++) {
          eLU[w] = aLU; aLU = max(aLU, wLU[w]);
          eLL[w] = aLL; aLL = max(aLL, wLL[w]);
          tt += wCT[w];
        }
        int aNU = NL, aNL = NL;
        for (int w = NW - 1; w >= 0; w--) {
          eNU[w] = aNU; aNU = min(aNU, wNU[w]);
          eNL[w] = aNL; aNL = min(aNL, wNL[w]);
        }
        sTot = tt;
      }
      __syncthreads();
      const unsigned tot = sTot;
      const int totU = (int)(tot >> 16), totL = (int)(tot & 0xffffu);

      // per-thread carries via ballot bit-ops + one dynamic shuffle each
      unsigned long long belowU = bUm & ((1ull << lane) - 1ull);
      unsigned long long belowL = bLm & ((1ull << lane) - 1ull);
      unsigned long long aboveU = (lane == 63) ? 0ull : (bUm & (~0ull << (lane + 1)));
      unsigned long long aboveL = (lane == 63) ? 0ull : (bLm & (~0ull << (lane + 1)));
      int slU = belowU ? (63 - __clzll((long long)belowU)) : 0;
      int slL = belowL ? (63 - __clzll((long long)belowL)) : 0;
      int snU = aboveU ? (__ffsll(aboveU) - 1) : 0;
      int snL = aboveL ? (__ffsll(aboveL) - 1) : 0;
      int gU  = __shfl(lmU, slU, 64);
      int gL  = __shfl(lmL, slL, 64);
      int gNU = __shfl(fpU, snU, 64);
      int gNL = __shfl(fpL, snL, 64);
      const int clU = belowU ? gU  : eLU[wv];
      const int clL = belowL ? gL  : eLL[wv];
      const int cnU = aboveU ? gNU : eNU[wv];
      const int cnL = aboveL ? gNL : eNL[wv];

      // Mx/Mn prefix carries only needed for the <2-peaks fallback (rare);
      // tot is block-uniform so the branch (and its barriers) is uniform.
      float crx = -FMAXV, crn = FMAXV;
      if (totU < 2 || totL < 2) {
        float iMx = rmx, iMn = rmn;
        #pragma unroll
        for (int o = 1; o < 64; o <<= 1) {
          float fa = __shfl_up(iMx, o, 64);
          float fb = __shfl_up(iMn, o, 64);
          if (lane >= o) { iMx = fmaxf(iMx, fa); iMn = fminf(iMn, fb); }
        }
        if (lane == 63) { wMx[wv] = iMx; wMn[wv] = iMn; }
        __syncthreads();
        if (t == 0) {
          float aMx = -FMAXV, aMn = FMAXV;
          for (int w = 0; w < NW; w++) {
            eMx[w] = aMx; aMx = fmaxf(aMx, wMx[w]);
            eMn[w] = aMn; aMn = fminf(aMn, wMn[w]);
          }
        }
        __syncthreads();
        float pMx = __shfl_up(iMx, 1, 64); if (lane == 0) pMx = -FMAXV;
        float pMn = __shfl_up(iMn, 1, 64); if (lane == 0) pMn = FMAXV;
        crx = fmaxf(eMx[wv], pMx);
        crn = fminf(eMn[wv], pMn);
      }

      // pass C: envelopes + mean (frozen f32 ladder). vl/wl roll in registers;
      // vr/wr cached LDS gathers; mean kept in registers.
      float mr[NC];
      double pm2 = 0.0, ph2 = 0.0;
      {
        float rx = crx, rn = crn;
        int curLU = clU, curLL = clL;
        float vl = h[physi(clU < 0 ? 0 : clU)];   // carry-in gathers (1 each)
        float wl = h[physi(clL < 0 ? 0 : clL)];
        int gB = -0x7fffffff, gD = -0x7fffffff;
        float vr = 0.0f, wr = 0.0f;
        #pragma unroll
        for (int j = 0; j < NC; j++) {
          int i = base + j;
          float hc = hr[j];
          rx = fmaxf(rx, hc);
          rn = fminf(rn, hc);
          if ((mU >> j) & 1u) { curLU = i; vl = hc; }   // own peak: value in reg
          if ((mL >> j) & 1u) { curLL = i; wl = hc; }
          int lU = curLU, lL = curLL;
          unsigned highm = 0xFFFFFFFFu << j;         // bits >= j
          unsigned a;
          a = mU & highm; int nUv = a ? (base + __ffs(a) - 1) : cnU;
          a = mL & highm; int nLv = a ? (base + __ffs(a) - 1) : cnL;
          if (nUv != gB) { gB = nUv; vr = h[physi(nUv >= NL ? NL - 1 : nUv)]; }
          if (nLv != gD) { gD = nLv; wr = h[physi(nLv >= NL ? NL - 1 : nLv)]; }
          int den = nUv - lU;
          float fracU = (float)(i - lU) / (float)(den > 0 ? den : 1);
          float envU = (den > 0) ? __builtin_fmaf(fracU, vr - vl, vl) : vl;
          if (lU < 0) envU = vr;
          if (nUv >= NL) envU = vl;
          if (totU < 2) envU = rx;
          int den2 = nLv - lL;
          float fracL = (float)(i - lL) / (float)(den2 > 0 ? den2 : 1);
          float envL = (den2 > 0) ? __builtin_fmaf(fracL, wr - wl, wl) : wl;
          if (lL < 0) envL = wr;
          if (nLv >= NL) envL = wl;
          if (totL < 2) envL = rn;
          float mn = 0.5f * (envU + envL);
          mr[j] = mn;
          pm2 += (double)mn * (double)mn;
          ph2 += (double)hc * (double)hc;
        }
      }
      // fused block reduction of (pm2, ph2): wave shuffle, publish, t0 combines
      #pragma unroll
      for (int o = 1; o < 64; o <<= 1) {
        double a = __shfl_down(pm2, o, 64);
        double b = __shfl_down(ph2, o, 64);
        if (lane + o < 64) { pm2 += a; ph2 += b; }
      }
      if (lane == 0) { tA[wv] = pm2; tB[wv] = ph2; }
      // ---- grid barrier + convergence decision ----
      ep++;
      __syncthreads();   // orders tA/tB before t0 reads
      if (t == 0) {
        double sA = 0.0, sB = 0.0;
        for (int w = 0; w < NW; w++) { sA += tA[w]; sB += tB[w]; }
        atomicAdd(&sdsl[(k * N_ITER + it) * 2 + 0], sA);
        atomicAdd(&sdsl[(k * N_ITER + it) * 2 + 1], sB);
        __hip_atomic_fetch_add(cnt, 1u, __ATOMIC_ACQ_REL, __HIP_MEMORY_SCOPE_AGENT);
        unsigned tgt = ep * gridDim.x;
        while (__hip_atomic_load(cnt, __ATOMIC_ACQUIRE, __HIP_MEMORY_SCOPE_AGENT) < tgt)
          __builtin_amdgcn_s_sleep(1);
        double m2 = __hip_atomic_load(&sdsl[(k * N_ITER + it) * 2 + 0],
                                      __ATOMIC_RELAXED, __HIP_MEMORY_SCOPE_AGENT);
        double h2 = __hip_atomic_load(&sdsl[(k * N_ITER + it) * 2 + 1],
                                      __ATOMIC_RELAXED, __HIP_MEMORY_SCOPE_AGENT);
        sFlag = (m2 / (h2 + 1e-8) < 0.05) ? 1 : 0;
      }
      __syncthreads();
      if (sFlag) break;   // converged: h frozen (JAX done-latch semantics)
      // subtract in registers, then write back h -> LDS (float4, swizzle-safe)
      #pragma unroll
      for (int j = 0; j < NC; j++) hr[j] -= mr[j];
      #pragma unroll
      for (int q = 0; q < NC / 4; q++) {
        int i0 = base + q * 4;
        *(float4*)&h[physi(i0)] = make_float4(hr[q * 4 + 0], hr[q * 4 + 1],
                                              hr[q * 4 + 2], hr[q * 4 + 3]);
      }
      __syncthreads();
    }

    // ------------- flatness test + outputs (f32 values, f64 sums) -------------
    float rv[NC];
    #pragma unroll
    for (int q = 0; q < NC / 4; q++) {
      float4 v = *(const float4*)&res[base + q * 4];
      rv[q * 4 + 0] = v.x; rv[q * 4 + 1] = v.y;
      rv[q * 4 + 2] = v.z; rv[q * 4 + 3] = v.w;
    }
    double s1 = 0.0, s2 = 0.0, s3 = 0.0, s4 = 0.0;
    {
      float rb = 0.0f;   // res-h at base+NC (next thread's first element)
      if (base + NC < NL) rb = res[base + NC] - h[physi(base + NC)];
      float rc = rv[0] - hr[0];
      #pragma unroll
      for (int j = 0; j < NC; j++) {
        int i = base + j;
        s1 += (double)rc;
        s2 += (double)rc * (double)rc;
        if (i + 1 < NL) {
          float rnx = (j + 1 < NC) ? (rv[j + 1] - hr[j + 1]) : rb;
          float d = rnx - rc;
          s3 += (double)d;
          s4 += (double)d * (double)d;
          rc = rnx;
        }
      }
    }
    #pragma unroll
    for (int o = 1; o < 64; o <<= 1) {
      double a = __shfl_down(s1, o, 64);
      double b = __shfl_down(s2, o, 64);
      double c = __shfl_down(s3, o, 64);
      double d = __shfl_down(s4, o, 64);
      if (lane + o < 64) { s1 += a; s2 += b; s3 += c; s4 += d; }
    }
    if (lane == 0) { tA[wv] = s1; tB[wv] = s2; tC[wv] = s3; tD[wv] = s4; }
    __syncthreads();   // orders publishes AND all cross-thread h/res reads above
    if (t == 0) {
      double S1 = 0.0, S2 = 0.0, S3 = 0.0, S4 = 0.0;
      for (int w = 0; w < NW; w++) { S1 += tA[w]; S2 += tB[w]; S3 += tC[w]; S4 += tD[w]; }
      atomicAdd(&flsl[k * 4 + 0], S1);
      atomicAdd(&flsl[k * 4 + 1], S2);
      atomicAdd(&flsl[k * 4 + 2], S3);
      atomicAdd(&flsl[k * 4 + 3], S4);
    }
    // outputs: IMF k = h; res -= h; h <- new res (regs + LDS)
    #pragma unroll
    for (int q = 0; q < NC / 4; q++) {
      int i0 = base + q * 4;
      float4 hv = make_float4(hr[q * 4 + 0], hr[q * 4 + 1],
                              hr[q * 4 + 2], hr[q * 4 + 3]);
      float4 rq = make_float4(rv[q * 4 + 0] - hv.x, rv[q * 4 + 1] - hv.y,
                              rv[q * 4 + 2] - hv.z, rv[q * 4 + 3] - hv.w);
      *(float4*)&outk[i0] = hv;
      *(float4*)&res[i0] = rq;
      *(float4*)&h[physi(i0)] = rq;
      hr[q * 4 + 0] = rq.x; hr[q * 4 + 1] = rq.y;
      hr[q * 4 + 2] = rq.z; hr[q * 4 + 3] = rq.w;
    }
    // ---- grid barrier + flatness decision ----
    ep++;
    __syncthreads();
    if (t == 0) {
      __hip_atomic_fetch_add(cnt, 1u, __ATOMIC_ACQ_REL, __HIP_MEMORY_SCOPE_AGENT);
      unsigned tgt = ep * gridDim.x;
      while (__hip_atomic_load(cnt, __ATOMIC_ACQUIRE, __HIP_MEMORY_SCOPE_AGENT) < tgt)
        __builtin_amdgcn_s_sleep(1);
      double S1 = __hip_atomic_load(&flsl[k * 4 + 0], __ATOMIC_RELAXED, __HIP_MEMORY_SCOPE_AGENT);
      double S2 = __hip_atomic_load(&flsl[k * 4 + 1], __ATOMIC_RELAXED, __HIP_MEMORY_SCOPE_AGENT);
      double S3 = __hip_atomic_load(&flsl[k * 4 + 2], __ATOMIC_RELAXED, __HIP_MEMORY_SCOPE_AGENT);
      double S4 = __hip_atomic_load(&flsl[k * 4 + 3], __ATOMIC_RELAXED, __HIP_MEMORY_SCOPE_AGENT);
      double nr = (double)NB * (double)NL;
      double nd = (double)NB * (double)(NL - 1);
      double varr = (S2 - S1 * S1 / nr) / (nr - 1.0);
      double vard = (S4 - S3 * S3 / nd) / (nd - 1.0);
      sFlag = (vard < 0.05 * varr) ? 1 : 0;
    }
    __syncthreads();
    done = done || (sFlag != 0);
  }
}

extern "C" void kernel_launch(void* const* d_in, const int* in_sizes, int n_in,
                              void* d_out, int out_size, void* d_ws, size_t ws_size,
                              hipStream_t stream) {
  const float* x = (const float*)d_in[0];
  float* out = (float*)d_out;
  // ws layout: [0] barrier counter; [256] sd slots (6*12*2 dbl); [1408] flat slots (6*4 dbl)
  size_t zb = ws_size < 4096 ? ws_size : 4096;
  hipMemsetAsync(d_ws, 0, zb, stream);
  unsigned* cnt = (unsigned*)d_ws;
  double* sdsl = (double*)((char*)d_ws + 256);
  double* flsl = (double*)((char*)d_ws + 256 + (size_t)N_IMFS * N_ITER * 2 * 8);
  hipLaunchKernelGGL(emd_main, dim3(NB), dim3(NT), 0, stream, x, out, cnt, sdsl, flsl);
}

// Round 4
// 450.424 us; speedup vs baseline: 1.0234x; 1.0234x over previous
//
#include <hip/hip_runtime.h>

#define NL 16384          // row length
#define NB 64             // rows = blocks
#define NT 1024           // threads per block (16 waves = 4 waves/SIMD)
#define NC (NL / NT)      // 16 elements per thread == bits in the peak mask
#define NW (NT / 64)      // 16 waves
#define N_ITER 12
#define N_IMFS 6

#pragma clang fp contract(off)   // everything unfused EXCEPT the explicit fmaf

#define HSZ (NL + (NL >> 5))   // +1 float per 32: 2-way-max banking (free)
__device__ __forceinline__ int physi(int i) { return i + (i >> 5); }

#define FMAXV 3.402823466e38f

// Frozen bit-exact semantics (certified R9/R11/R13, absmax 0.0).
// R12: NT 512->1024 (occ 6->12%), 283->251us; VALUBusy flat -> DS-pipe bound.
// R13 (DS diet): h in VGPRs, meanb eliminated, scans -> ballot+1shfl. FAILED
// 404us: 69KB LDS lets 2 blocks/CU fit -> hipcc occupancy heuristic targets
// 8 waves/EU -> VGPRs squeezed to 64 -> mr/rv spill (203MB scratch writes).
// R14: amdgpu_waves_per_eu(4,4) was INERT (identical VGPR=64 + scratch).
// R15: force the target via the channel the compiler can't ignore: LDS pad
// (16KB, volatile-kept) -> static LDS 85.5KB > 80KB -> 2 blocks/CU physically
// impossible -> occupancy target 4 waves/EU -> 128-VGPR budget -> arrays in
// registers. Grid is 64 blocks on 256 CUs, so 2 blocks/CU was unreachable
// anyway. Value path byte-identical to R13/R14.
__global__ __launch_bounds__(NT, 4) void emd_main(
    const float* __restrict__ x, float* __restrict__ out,
    unsigned* cnt, double* sdsl, double* flsl) {
  __shared__ float h[HSZ];        // 67584 B (only big live LDS buffer)
  volatile __shared__ float lpad[4096];  // 16384 B occupancy clamp (see R15)
  __shared__ int wLU[NW], wLL[NW], wNU[NW], wNL[NW];
  __shared__ float wMx[NW], wMn[NW];
  __shared__ unsigned wCT[NW];
  __shared__ int eLU[NW], eLL[NW], eNU[NW], eNL[NW];
  __shared__ float eMx[NW], eMn[NW];
  __shared__ unsigned sTot;
  __shared__ double tA[NW], tB[NW], tC[NW], tD[NW];
  __shared__ int sFlag;

  const int t = threadIdx.x;
  const int lane = t & 63;
  const int wv = t >> 6;
  const int row = blockIdx.x;
  const int base = t * NC;
  const float* xr = x + (size_t)row * NL;
  float* res = out + (size_t)N_IMFS * NB * NL + (size_t)row * NL;

  if (t == 0) lpad[0] = 0.0f;   // volatile: keeps the clamp array allocated

  float hr[NC];   // register-resident h (always == LDS h after each barrier)

  // init: h = x row (regs + LDS, swizzled); res slab of d_out = x
  #pragma unroll
  for (int q = 0; q < NC / 4; q++) {
    int i0 = base + q * 4;
    float4 v = *(const float4*)&xr[i0];
    hr[q * 4 + 0] = v.x; hr[q * 4 + 1] = v.y;
    hr[q * 4 + 2] = v.z; hr[q * 4 + 3] = v.w;
    *(float4*)&h[physi(i0)] = v;
    *(float4*)&res[i0] = v;
  }
  __syncthreads();

  unsigned ep = 0;
  bool done = false;

  for (int k = 0; k < N_IMFS; k++) {
    float* outk = out + (size_t)k * NB * NL + (size_t)row * NL;
    if (done) {  // globally-uniform skip (no barriers)
      #pragma unroll
      for (int q = 0; q < NC / 4; q++)
        *(float4*)&outk[base + q * 4] = make_float4(0.f, 0.f, 0.f, 0.f);
      continue;
    }

    // ---------------- sifting ----------------
    for (int it = 0; it < N_ITER; it++) {
      // pass A: rolling walk over registers -> peak masks + chunk summaries
      unsigned mU = 0, mL = 0;
      int lmU = -1, lmL = -1, cU = 0, cL = 0;
      float rmx = -FMAXV, rmn = FMAXV;
      {
        float hm = (base > 0) ? h[physi(base - 1)] : 0.0f;   // neighbor (LDS)
        #pragma unroll
        for (int j = 0; j < NC; j++) {
          int i = base + j;
          float hc = hr[j];
          float hp = (j + 1 < NC) ? hr[j + 1]
                                  : ((i + 1 < NL) ? h[physi(i + 1)] : 0.0f);
          bool in = (i > 0) && (i + 1 < NL);
          if (in && hm < hc && hc > hp) { mU |= (1u << j); lmU = i; cU++; }
          if (in && hm > hc && hc < hp) { mL |= (1u << j); lmL = i; cL++; }
          rmx = fmaxf(rmx, hc);
          rmn = fminf(rmn, hc);
          hm = hc;
        }
      }
      int fpU = mU ? (base + __ffs(mU) - 1) : NL;   // first own peak
      int fpL = mL ? (base + __ffs(mL) - 1) : NL;
      unsigned long long bUm = __ballot(mU != 0);
      unsigned long long bLm = __ballot(mL != 0);
      // wave summaries: owning lane stores directly (no scans)
      {
        int s;
        s = bUm ? (63 - __clzll((long long)bUm)) : 0;
        if (lane == s) wLU[wv] = bUm ? lmU : -1;
        s = bLm ? (63 - __clzll((long long)bLm)) : 0;
        if (lane == s) wLL[wv] = bLm ? lmL : -1;
        s = bUm ? (__ffsll(bUm) - 1) : 0;
        if (lane == s) wNU[wv] = bUm ? fpU : NL;
        s = bLm ? (__ffsll(bLm) - 1) : 0;
        if (lane == s) wNL[wv] = bLm ? fpL : NL;
      }
      // block peak-count totals (reduce only; same pairwise order as before)
      unsigned ict = ((unsigned)cU << 16) | (unsigned)cL;
      #pragma unroll
      for (int o = 1; o < 64; o <<= 1) {
        unsigned cc = __shfl_down(ict, o, 64);
        if (lane + o < 64) ict += cc;
      }
      if (lane == 0) wCT[wv] = ict;
      __syncthreads();
      if (t == 0) {  // 16-entry serial combine -> exclusive wave carries
        int aLU = -1, aLL = -1; unsigned tt = 0;
        for (int w = 0; w < NW; w++) {
          eLU[w] = aLU; aLU = max(aLU, wLU[w]);
          eLL[w] = aLL; aLL = max(aLL, wLL[w]);
          tt += wCT[w];
        }
        int aNU = NL, aNL = NL;
        for (int w = NW - 1; w >= 0; w--) {
          eNU[w] = aNU; aNU = min(aNU, wNU[w]);
          eNL[w] = aNL; aNL = min(aNL, wNL[w]);
        }
        sTot = tt;
      }
      __syncthreads();
      const unsigned tot = sTot;
      const int totU = (int)(tot >> 16), totL = (int)(tot & 0xffffu);

      // per-thread carries via ballot bit-ops + one dynamic shuffle each
      unsigned long long belowU = bUm & ((1ull << lane) - 1ull);
      unsigned long long belowL = bLm & ((1ull << lane) - 1ull);
      unsigned long long aboveU = (lane == 63) ? 0ull : (bUm & (~0ull << (lane + 1)));
      unsigned long long aboveL = (lane == 63) ? 0ull : (bLm & (~0ull << (lane + 1)));
      int slU = belowU ? (63 - __clzll((long long)belowU)) : 0;
      int slL = belowL ? (63 - __clzll((long long)belowL)) : 0;
      int snU = aboveU ? (__ffsll(aboveU) - 1) : 0;
      int snL = aboveL ? (__ffsll(aboveL) - 1) : 0;
      int gU  = __shfl(lmU, slU, 64);
      int gL  = __shfl(lmL, slL, 64);
      int gNU = __shfl(fpU, snU, 64);
      int gNL = __shfl(fpL, snL, 64);
      const int clU = belowU ? gU  : eLU[wv];
      const int clL = belowL ? gL  : eLL[wv];
      const int cnU = aboveU ? gNU : eNU[wv];
      const int cnL = aboveL ? gNL : eNL[wv];

      // Mx/Mn prefix carries only needed for the <2-peaks fallback (rare);
      // tot is block-uniform so the branch (and its barriers) is uniform.
      float crx = -FMAXV, crn = FMAXV;
      if (totU < 2 || totL < 2) {
        float iMx = rmx, iMn = rmn;
        #pragma unroll
        for (int o = 1; o < 64; o <<= 1) {
          float fa = __shfl_up(iMx, o, 64);
          float fb = __shfl_up(iMn, o, 64);
          if (lane >= o) { iMx = fmaxf(iMx, fa); iMn = fminf(iMn, fb); }
        }
        if (lane == 63) { wMx[wv] = iMx; wMn[wv] = iMn; }
        __syncthreads();
        if (t == 0) {
          float aMx = -FMAXV, aMn = FMAXV;
          for (int w = 0; w < NW; w++) {
            eMx[w] = aMx; aMx = fmaxf(aMx, wMx[w]);
            eMn[w] = aMn; aMn = fminf(aMn, wMn[w]);
          }
        }
        __syncthreads();
        float pMx = __shfl_up(iMx, 1, 64); if (lane == 0) pMx = -FMAXV;
        float pMn = __shfl_up(iMn, 1, 64); if (lane == 0) pMn = FMAXV;
        crx = fmaxf(eMx[wv], pMx);
        crn = fminf(eMn[wv], pMn);
      }

      // pass C: envelopes + mean (frozen f32 ladder). vl/wl roll in registers;
      // vr/wr cached LDS gathers; mean kept in registers.
      float mr[NC];
      double pm2 = 0.0, ph2 = 0.0;
      {
        float rx = crx, rn = crn;
        int curLU = clU, curLL = clL;
        float vl = h[physi(clU < 0 ? 0 : clU)];   // carry-in gathers (1 each)
        float wl = h[physi(clL < 0 ? 0 : clL)];
        int gB = -0x7fffffff, gD = -0x7fffffff;
        float vr = 0.0f, wr = 0.0f;
        #pragma unroll
        for (int j = 0; j < NC; j++) {
          int i = base + j;
          float hc = hr[j];
          rx = fmaxf(rx, hc);
          rn = fminf(rn, hc);
          if ((mU >> j) & 1u) { curLU = i; vl = hc; }   // own peak: value in reg
          if ((mL >> j) & 1u) { curLL = i; wl = hc; }
          int lU = curLU, lL = curLL;
          unsigned highm = 0xFFFFFFFFu << j;         // bits >= j
          unsigned a;
          a = mU & highm; int nUv = a ? (base + __ffs(a) - 1) : cnU;
          a = mL & highm; int nLv = a ? (base + __ffs(a) - 1) : cnL;
          if (nUv != gB) { gB = nUv; vr = h[physi(nUv >= NL ? NL - 1 : nUv)]; }
          if (nLv != gD) { gD = nLv; wr = h[physi(nLv >= NL ? NL - 1 : nLv)]; }
          int den = nUv - lU;
          float fracU = (float)(i - lU) / (float)(den > 0 ? den : 1);
          float envU = (den > 0) ? __builtin_fmaf(fracU, vr - vl, vl) : vl;
          if (lU < 0) envU = vr;
          if (nUv >= NL) envU = vl;
          if (totU < 2) envU = rx;
          int den2 = nLv - lL;
          float fracL = (float)(i - lL) / (float)(den2 > 0 ? den2 : 1);
          float envL = (den2 > 0) ? __builtin_fmaf(fracL, wr - wl, wl) : wl;
          if (lL < 0) envL = wr;
          if (nLv >= NL) envL = wl;
          if (totL < 2) envL = rn;
          float mn = 0.5f * (envU + envL);
          mr[j] = mn;
          pm2 += (double)mn * (double)mn;
          ph2 += (double)hc * (double)hc;
        }
      }
      // fused block reduction of (pm2, ph2): wave shuffle, publish, t0 combines
      #pragma unroll
      for (int o = 1; o < 64; o <<= 1) {
        double a = __shfl_down(pm2, o, 64);
        double b = __shfl_down(ph2, o, 64);
        if (lane + o < 64) { pm2 += a; ph2 += b; }
      }
      if (lane == 0) { tA[wv] = pm2; tB[wv] = ph2; }
      // ---- grid barrier + convergence decision ----
      ep++;
      __syncthreads();   // orders tA/tB before t0 reads
      if (t == 0) {
        double sA = 0.0, sB = 0.0;
        for (int w = 0; w < NW; w++) { sA += tA[w]; sB += tB[w]; }
        atomicAdd(&sdsl[(k * N_ITER + it) * 2 + 0], sA);
        atomicAdd(&sdsl[(k * N_ITER + it) * 2 + 1], sB);
        __hip_atomic_fetch_add(cnt, 1u, __ATOMIC_ACQ_REL, __HIP_MEMORY_SCOPE_AGENT);
        unsigned tgt = ep * gridDim.x;
        while (__hip_atomic_load(cnt, __ATOMIC_ACQUIRE, __HIP_MEMORY_SCOPE_AGENT) < tgt)
          __builtin_amdgcn_s_sleep(1);
        double m2 = __hip_atomic_load(&sdsl[(k * N_ITER + it) * 2 + 0],
                                      __ATOMIC_RELAXED, __HIP_MEMORY_SCOPE_AGENT);
        double h2 = __hip_atomic_load(&sdsl[(k * N_ITER + it) * 2 + 1],
                                      __ATOMIC_RELAXED, __HIP_MEMORY_SCOPE_AGENT);
        sFlag = (m2 / (h2 + 1e-8) < 0.05) ? 1 : 0;
      }
      __syncthreads();
      if (sFlag) break;   // converged: h frozen (JAX done-latch semantics)
      // subtract in registers, then write back h -> LDS (float4, swizzle-safe)
      #pragma unroll
      for (int j = 0; j < NC; j++) hr[j] -= mr[j];
      #pragma unroll
      for (int q = 0; q < NC / 4; q++) {
        int i0 = base + q * 4;
        *(float4*)&h[physi(i0)] = make_float4(hr[q * 4 + 0], hr[q * 4 + 1],
                                              hr[q * 4 + 2], hr[q * 4 + 3]);
      }
      __syncthreads();
    }

    // ------------- flatness test + outputs (f32 values, f64 sums) -------------
    float rv[NC];
    #pragma unroll
    for (int q = 0; q < NC / 4; q++) {
      float4 v = *(const float4*)&res[base + q * 4];
      rv[q * 4 + 0] = v.x; rv[q * 4 + 1] = v.y;
      rv[q * 4 + 2] = v.z; rv[q * 4 + 3] = v.w;
    }
    double s1 = 0.0, s2 = 0.0, s3 = 0.0, s4 = 0.0;
    {
      float rb = 0.0f;   // res-h at base+NC (next thread's first element)
      if (base + NC < NL) rb = res[base + NC] - h[physi(base + NC)];
      float rc = rv[0] - hr[0];
      #pragma unroll
      for (int j = 0; j < NC; j++) {
        int i = base + j;
        s1 += (double)rc;
        s2 += (double)rc * (double)rc;
        if (i + 1 < NL) {
          float rnx = (j + 1 < NC) ? (rv[j + 1] - hr[j + 1]) : rb;
          float d = rnx - rc;
          s3 += (double)d;
          s4 += (double)d * (double)d;
          rc = rnx;
        }
      }
    }
    #pragma unroll
    for (int o = 1; o < 64; o <<= 1) {
      double a = __shfl_down(s1, o, 64);
      double b = __shfl_down(s2, o, 64);
      double c = __shfl_down(s3, o, 64);
      double d = __shfl_down(s4, o, 64);
      if (lane + o < 64) { s1 += a; s2 += b; s3 += c; s4 += d; }
    }
    if (lane == 0) { tA[wv] = s1; tB[wv] = s2; tC[wv] = s3; tD[wv] = s4; }
    __syncthreads();   // orders publishes AND all cross-thread h/res reads above
    if (t == 0) {
      double S1 = 0.0, S2 = 0.0, S3 = 0.0, S4 = 0.0;
      for (int w = 0; w < NW; w++) { S1 += tA[w]; S2 += tB[w]; S3 += tC[w]; S4 += tD[w]; }
      atomicAdd(&flsl[k * 4 + 0], S1);
      atomicAdd(&flsl[k * 4 + 1], S2);
      atomicAdd(&flsl[k * 4 + 2], S3);
      atomicAdd(&flsl[k * 4 + 3], S4);
    }
    // outputs: IMF k = h; res -= h; h <- new res (regs + LDS)
    #pragma unroll
    for (int q = 0; q < NC / 4; q++) {
      int i0 = base + q * 4;
      float4 hv = make_float4(hr[q * 4 + 0], hr[q * 4 + 1],
                              hr[q * 4 + 2], hr[q * 4 + 3]);
      float4 rq = make_float4(rv[q * 4 + 0] - hv.x, rv[q * 4 + 1] - hv.y,
                              rv[q * 4 + 2] - hv.z, rv[q * 4 + 3] - hv.w);
      *(float4*)&outk[i0] = hv;
      *(float4*)&res[i0] = rq;
      *(float4*)&h[physi(i0)] = rq;
      hr[q * 4 + 0] = rq.x; hr[q * 4 + 1] = rq.y;
      hr[q * 4 + 2] = rq.z; hr[q * 4 + 3] = rq.w;
    }
    // ---- grid barrier + flatness decision ----
    ep++;
    __syncthreads();
    if (t == 0) {
      __hip_atomic_fetch_add(cnt, 1u, __ATOMIC_ACQ_REL, __HIP_MEMORY_SCOPE_AGENT);
      unsigned tgt = ep * gridDim.x;
      while (__hip_atomic_load(cnt, __ATOMIC_ACQUIRE, __HIP_MEMORY_SCOPE_AGENT) < tgt)
        __builtin_amdgcn_s_sleep(1);
      double S1 = __hip_atomic_load(&flsl[k * 4 + 0], __ATOMIC_RELAXED, __HIP_MEMORY_SCOPE_AGENT);
      double S2 = __hip_atomic_load(&flsl[k * 4 + 1], __ATOMIC_RELAXED, __HIP_MEMORY_SCOPE_AGENT);
      double S3 = __hip_atomic_load(&flsl[k * 4 + 2], __ATOMIC_RELAXED, __HIP_MEMORY_SCOPE_AGENT);
      double S4 = __hip_atomic_load(&flsl[k * 4 + 3], __ATOMIC_RELAXED, __HIP_MEMORY_SCOPE_AGENT);
      double nr = (double)NB * (double)NL;
      double nd = (double)NB * (double)(NL - 1);
      double varr = (S2 - S1 * S1 / nr) / (nr - 1.0);
      double vard = (S4 - S3 * S3 / nd) / (nd - 1.0);
      sFlag = (vard < 0.05 * varr) ? 1 : 0;
    }
    __syncthreads();
    done = done || (sFlag != 0);
  }
}

extern "C" void kernel_launch(void* const* d_in, const int* in_sizes, int n_in,
                              void* d_out, int out_size, void* d_ws, size_t ws_size,
                              hipStream_t stream) {
  const float* x = (const float*)d_in[0];
  float* out = (float*)d_out;
  // ws layout: [0] barrier counter; [256] sd slots (6*12*2 dbl); [1408] flat slots (6*4 dbl)
  size_t zb = ws_size < 4096 ? ws_size : 4096;
  hipMemsetAsync(d_ws, 0, zb, stream);
  unsigned* cnt = (unsigned*)d_ws;
  double* sdsl = (double*)((char*)d_ws + 256);
  double* flsl = (double*)((char*)d_ws + 256 + (size_t)N_IMFS * N_ITER * 2 * 8);
  hipLaunchKernelGGL(emd_main, dim3(NB), dim3(NT), 0, stream, x, out, cnt, sdsl, flsl);
}

// Round 5
// 433.945 us; speedup vs baseline: 1.0622x; 1.0380x over previous
//
#include <hip/hip_runtime.h>

#define NL 16384          // row length
#define NB 64             // rows = blocks
#define NT 1024           // threads per block (16 waves = 4 waves/SIMD)
#define NC (NL / NT)      // 16 elements per thread == bits in the peak mask
#define NW (NT / 64)      // 16 waves
#define N_ITER 12
#define N_IMFS 6

#pragma clang fp contract(off)   // everything unfused EXCEPT the explicit fmaf

#define HSZ (NL + (NL >> 5))   // +1 float per 32: 2-way-max banking (free)
__device__ __forceinline__ int physi(int i) { return i + (i >> 5); }

#define FMAXV 3.402823466e38f

// First-class vector locals: no alloca -> PromoteAlloca/SROA not involved ->
// cannot land in scratch. Subscripts are extract/insertelement and fold to
// constants after full unroll.
typedef float vf16 __attribute__((ext_vector_type(16)));
static_assert(NC == 16, "vf16 layout assumes NC==16");

// Frozen bit-exact semantics (certified R9/R11/R13, absmax 0.0).
// R12: NT 512->1024 (occ 6->12%), 283->251us; VALUBusy flat -> DS-pipe bound.
// R13 (DS diet): h/mean/res chunks as float[16] privates. 404us: ~170MB
// scratch traffic, VGPR pinned at 64.
// R14 (waves_per_eu(4,4)): inert. R15 (LDS pad >80KB, blocks 2/CU): inert.
// => spill is NOT a regalloc budget issue: PromoteAlloca refuses to promote
// 3x16-float private ARRAYS (internal budget), leaving allocas in scratch,
// insensitive to every occupancy hint.
// R16: arrays -> ext_vector_type(16) SSA values (hr/mr/rv). No allocas at
// all; regalloc cap 128 comes from the 1024-thread workgroup launchability.
// Value path byte-identical to R13-R15. LDS pad dropped.
__global__ __attribute__((amdgpu_flat_work_group_size(NT, NT),
                          amdgpu_waves_per_eu(4, 4)))
void emd_main(
    const float* __restrict__ x, float* __restrict__ out,
    unsigned* cnt, double* sdsl, double* flsl) {
  __shared__ float h[HSZ];        // 67584 B (only big LDS buffer)
  __shared__ int wLU[NW], wLL[NW], wNU[NW], wNL[NW];
  __shared__ float wMx[NW], wMn[NW];
  __shared__ unsigned wCT[NW];
  __shared__ int eLU[NW], eLL[NW], eNU[NW], eNL[NW];
  __shared__ float eMx[NW], eMn[NW];
  __shared__ unsigned sTot;
  __shared__ double tA[NW], tB[NW], tC[NW], tD[NW];
  __shared__ int sFlag;

  const int t = threadIdx.x;
  const int lane = t & 63;
  const int wv = t >> 6;
  const int row = blockIdx.x;
  const int base = t * NC;
  const float* xr = x + (size_t)row * NL;
  float* res = out + (size_t)N_IMFS * NB * NL + (size_t)row * NL;

  vf16 hr;   // register-resident h (always == LDS h after each barrier)

  // init: h = x row (regs + LDS, swizzled); res slab of d_out = x
  #pragma unroll
  for (int q = 0; q < NC / 4; q++) {
    int i0 = base + q * 4;
    float4 v = *(const float4*)&xr[i0];
    hr[q * 4 + 0] = v.x; hr[q * 4 + 1] = v.y;
    hr[q * 4 + 2] = v.z; hr[q * 4 + 3] = v.w;
    *(float4*)&h[physi(i0)] = v;
    *(float4*)&res[i0] = v;
  }
  __syncthreads();

  unsigned ep = 0;
  bool done = false;

  for (int k = 0; k < N_IMFS; k++) {
    float* outk = out + (size_t)k * NB * NL + (size_t)row * NL;
    if (done) {  // globally-uniform skip (no barriers)
      #pragma unroll
      for (int q = 0; q < NC / 4; q++)
        *(float4*)&outk[base + q * 4] = make_float4(0.f, 0.f, 0.f, 0.f);
      continue;
    }

    // ---------------- sifting ----------------
    for (int it = 0; it < N_ITER; it++) {
      // pass A: rolling walk over registers -> peak masks + chunk summaries
      unsigned mU = 0, mL = 0;
      int lmU = -1, lmL = -1, cU = 0, cL = 0;
      float rmx = -FMAXV, rmn = FMAXV;
      {
        float hm = (base > 0) ? h[physi(base - 1)] : 0.0f;   // neighbor (LDS)
        #pragma unroll
        for (int j = 0; j < NC; j++) {
          int i = base + j;
          float hc = hr[j];
          float hp = (j + 1 < NC) ? hr[(j + 1) & 15]
                                  : ((i + 1 < NL) ? h[physi(i + 1)] : 0.0f);
          bool in = (i > 0) && (i + 1 < NL);
          if (in && hm < hc && hc > hp) { mU |= (1u << j); lmU = i; cU++; }
          if (in && hm > hc && hc < hp) { mL |= (1u << j); lmL = i; cL++; }
          rmx = fmaxf(rmx, hc);
          rmn = fminf(rmn, hc);
          hm = hc;
        }
      }
      int fpU = mU ? (base + __ffs(mU) - 1) : NL;   // first own peak
      int fpL = mL ? (base + __ffs(mL) - 1) : NL;
      unsigned long long bUm = __ballot(mU != 0);
      unsigned long long bLm = __ballot(mL != 0);
      // wave summaries: owning lane stores directly (no scans)
      {
        int s;
        s = bUm ? (63 - __clzll((long long)bUm)) : 0;
        if (lane == s) wLU[wv] = bUm ? lmU : -1;
        s = bLm ? (63 - __clzll((long long)bLm)) : 0;
        if (lane == s) wLL[wv] = bLm ? lmL : -1;
        s = bUm ? (__ffsll(bUm) - 1) : 0;
        if (lane == s) wNU[wv] = bUm ? fpU : NL;
        s = bLm ? (__ffsll(bLm) - 1) : 0;
        if (lane == s) wNL[wv] = bLm ? fpL : NL;
      }
      // block peak-count totals (reduce only; same pairwise order as before)
      unsigned ict = ((unsigned)cU << 16) | (unsigned)cL;
      #pragma unroll
      for (int o = 1; o < 64; o <<= 1) {
        unsigned cc = __shfl_down(ict, o, 64);
        if (lane + o < 64) ict += cc;
      }
      if (lane == 0) wCT[wv] = ict;
      __syncthreads();
      if (t == 0) {  // 16-entry serial combine -> exclusive wave carries
        int aLU = -1, aLL = -1; unsigned tt = 0;
        for (int w = 0; w < NW; w++) {
          eLU[w] = aLU; aLU = max(aLU, wLU[w]);
          eLL[w] = aLL; aLL = max(aLL, wLL[w]);
          tt += wCT[w];
        }
        int aNU = NL, aNL = NL;
        for (int w = NW - 1; w >= 0; w--) {
          eNU[w] = aNU; aNU = min(aNU, wNU[w]);
          eNL[w] = aNL; aNL = min(aNL, wNL[w]);
        }
        sTot = tt;
      }
      __syncthreads();
      const unsigned tot = sTot;
      const int totU = (int)(tot >> 16), totL = (int)(tot & 0xffffu);

      // per-thread carries via ballot bit-ops + one dynamic shuffle each
      unsigned long long belowU = bUm & ((1ull << lane) - 1ull);
      unsigned long long belowL = bLm & ((1ull << lane) - 1ull);
      unsigned long long aboveU = (lane == 63) ? 0ull : (bUm & (~0ull << (lane + 1)));
      unsigned long long aboveL = (lane == 63) ? 0ull : (bLm & (~0ull << (lane + 1)));
      int slU = belowU ? (63 - __clzll((long long)belowU)) : 0;
      int slL = belowL ? (63 - __clzll((long long)belowL)) : 0;
      int snU = aboveU ? (__ffsll(aboveU) - 1) : 0;
      int snL = aboveL ? (__ffsll(aboveL) - 1) : 0;
      int gU  = __shfl(lmU, slU, 64);
      int gL  = __shfl(lmL, slL, 64);
      int gNU = __shfl(fpU, snU, 64);
      int gNL = __shfl(fpL, snL, 64);
      const int clU = belowU ? gU  : eLU[wv];
      const int clL = belowL ? gL  : eLL[wv];
      const int cnU = aboveU ? gNU : eNU[wv];
      const int cnL = aboveL ? gNL : eNL[wv];

      // Mx/Mn prefix carries only needed for the <2-peaks fallback (rare);
      // tot is block-uniform so the branch (and its barriers) is uniform.
      float crx = -FMAXV, crn = FMAXV;
      if (totU < 2 || totL < 2) {
        float iMx = rmx, iMn = rmn;
        #pragma unroll
        for (int o = 1; o < 64; o <<= 1) {
          float fa = __shfl_up(iMx, o, 64);
          float fb = __shfl_up(iMn, o, 64);
          if (lane >= o) { iMx = fmaxf(iMx, fa); iMn = fminf(iMn, fb); }
        }
        if (lane == 63) { wMx[wv] = iMx; wMn[wv] = iMn; }
        __syncthreads();
        if (t == 0) {
          float aMx = -FMAXV, aMn = FMAXV;
          for (int w = 0; w < NW; w++) {
            eMx[w] = aMx; aMx = fmaxf(aMx, wMx[w]);
            eMn[w] = aMn; aMn = fminf(aMn, wMn[w]);
          }
        }
        __syncthreads();
        float pMx = __shfl_up(iMx, 1, 64); if (lane == 0) pMx = -FMAXV;
        float pMn = __shfl_up(iMn, 1, 64); if (lane == 0) pMn = FMAXV;
        crx = fmaxf(eMx[wv], pMx);
        crn = fminf(eMn[wv], pMn);
      }

      // pass C: envelopes + mean (frozen f32 ladder). vl/wl roll in registers;
      // vr/wr cached LDS gathers; mean kept in a vector register.
      vf16 mr;
      double pm2 = 0.0, ph2 = 0.0;
      {
        float rx = crx, rn = crn;
        int curLU = clU, curLL = clL;
        float vl = h[physi(clU < 0 ? 0 : clU)];   // carry-in gathers (1 each)
        float wl = h[physi(clL < 0 ? 0 : clL)];
        int gB = -0x7fffffff, gD = -0x7fffffff;
        float vr = 0.0f, wr = 0.0f;
        #pragma unroll
        for (int j = 0; j < NC; j++) {
          int i = base + j;
          float hc = hr[j];
          rx = fmaxf(rx, hc);
          rn = fminf(rn, hc);
          if ((mU >> j) & 1u) { curLU = i; vl = hc; }   // own peak: value in reg
          if ((mL >> j) & 1u) { curLL = i; wl = hc; }
          int lU = curLU, lL = curLL;
          unsigned highm = 0xFFFFFFFFu << j;         // bits >= j
          unsigned a;
          a = mU & highm; int nUv = a ? (base + __ffs(a) - 1) : cnU;
          a = mL & highm; int nLv = a ? (base + __ffs(a) - 1) : cnL;
          if (nUv != gB) { gB = nUv; vr = h[physi(nUv >= NL ? NL - 1 : nUv)]; }
          if (nLv != gD) { gD = nLv; wr = h[physi(nLv >= NL ? NL - 1 : nLv)]; }
          int den = nUv - lU;
          float fracU = (float)(i - lU) / (float)(den > 0 ? den : 1);
          float envU = (den > 0) ? __builtin_fmaf(fracU, vr - vl, vl) : vl;
          if (lU < 0) envU = vr;
          if (nUv >= NL) envU = vl;
          if (totU < 2) envU = rx;
          int den2 = nLv - lL;
          float fracL = (float)(i - lL) / (float)(den2 > 0 ? den2 : 1);
          float envL = (den2 > 0) ? __builtin_fmaf(fracL, wr - wl, wl) : wl;
          if (lL < 0) envL = wr;
          if (nLv >= NL) envL = wl;
          if (totL < 2) envL = rn;
          float mn = 0.5f * (envU + envL);
          mr[j] = mn;
          pm2 += (double)mn * (double)mn;
          ph2 += (double)hc * (double)hc;
        }
      }
      // fused block reduction of (pm2, ph2): wave shuffle, publish, t0 combines
      #pragma unroll
      for (int o = 1; o < 64; o <<= 1) {
        double a = __shfl_down(pm2, o, 64);
        double b = __shfl_down(ph2, o, 64);
        if (lane + o < 64) { pm2 += a; ph2 += b; }
      }
      if (lane == 0) { tA[wv] = pm2; tB[wv] = ph2; }
      // ---- grid barrier + convergence decision ----
      ep++;
      __syncthreads();   // orders tA/tB before t0 reads
      if (t == 0) {
        double sA = 0.0, sB = 0.0;
        for (int w = 0; w < NW; w++) { sA += tA[w]; sB += tB[w]; }
        atomicAdd(&sdsl[(k * N_ITER + it) * 2 + 0], sA);
        atomicAdd(&sdsl[(k * N_ITER + it) * 2 + 1], sB);
        __hip_atomic_fetch_add(cnt, 1u, __ATOMIC_ACQ_REL, __HIP_MEMORY_SCOPE_AGENT);
        unsigned tgt = ep * gridDim.x;
        while (__hip_atomic_load(cnt, __ATOMIC_ACQUIRE, __HIP_MEMORY_SCOPE_AGENT) < tgt)
          __builtin_amdgcn_s_sleep(1);
        double m2 = __hip_atomic_load(&sdsl[(k * N_ITER + it) * 2 + 0],
                                      __ATOMIC_RELAXED, __HIP_MEMORY_SCOPE_AGENT);
        double h2 = __hip_atomic_load(&sdsl[(k * N_ITER + it) * 2 + 1],
                                      __ATOMIC_RELAXED, __HIP_MEMORY_SCOPE_AGENT);
        sFlag = (m2 / (h2 + 1e-8) < 0.05) ? 1 : 0;
      }
      __syncthreads();
      if (sFlag) break;   // converged: h frozen (JAX done-latch semantics)
      // subtract in registers, then write back h -> LDS (float4, swizzle-safe)
      #pragma unroll
      for (int j = 0; j < NC; j++) hr[j] -= mr[j];
      #pragma unroll
      for (int q = 0; q < NC / 4; q++) {
        int i0 = base + q * 4;
        *(float4*)&h[physi(i0)] = make_float4(hr[q * 4 + 0], hr[q * 4 + 1],
                                              hr[q * 4 + 2], hr[q * 4 + 3]);
      }
      __syncthreads();
    }

    // ------------- flatness test + outputs (f32 values, f64 sums) -------------
    vf16 rv;
    #pragma unroll
    for (int q = 0; q < NC / 4; q++) {
      float4 v = *(const float4*)&res[base + q * 4];
      rv[q * 4 + 0] = v.x; rv[q * 4 + 1] = v.y;
      rv[q * 4 + 2] = v.z; rv[q * 4 + 3] = v.w;
    }
    double s1 = 0.0, s2 = 0.0, s3 = 0.0, s4 = 0.0;
    {
      float rb = 0.0f;   // res-h at base+NC (next thread's first element)
      if (base + NC < NL) rb = res[base + NC] - h[physi(base + NC)];
      float rc = rv[0] - hr[0];
      #pragma unroll
      for (int j = 0; j < NC; j++) {
        int i = base + j;
        s1 += (double)rc;
        s2 += (double)rc * (double)rc;
        if (i + 1 < NL) {
          float rnx = (j + 1 < NC) ? (rv[(j + 1) & 15] - hr[(j + 1) & 15]) : rb;
          float d = rnx - rc;
          s3 += (double)d;
          s4 += (double)d * (double)d;
          rc = rnx;
        }
      }
    }
    #pragma unroll
    for (int o = 1; o < 64; o <<= 1) {
      double a = __shfl_down(s1, o, 64);
      double b = __shfl_down(s2, o, 64);
      double c = __shfl_down(s3, o, 64);
      double d = __shfl_down(s4, o, 64);
      if (lane + o < 64) { s1 += a; s2 += b; s3 += c; s4 += d; }
    }
    if (lane == 0) { tA[wv] = s1; tB[wv] = s2; tC[wv] = s3; tD[wv] = s4; }
    __syncthreads();   // orders publishes AND all cross-thread h/res reads above
    if (t == 0) {
      double S1 = 0.0, S2 = 0.0, S3 = 0.0, S4 = 0.0;
      for (int w = 0; w < NW; w++) { S1 += tA[w]; S2 += tB[w]; S3 += tC[w]; S4 += tD[w]; }
      atomicAdd(&flsl[k * 4 + 0], S1);
      atomicAdd(&flsl[k * 4 + 1], S2);
      atomicAdd(&flsl[k * 4 + 2], S3);
      atomicAdd(&flsl[k * 4 + 3], S4);
    }
    // outputs: IMF k = h; res -= h; h <- new res (regs + LDS)
    #pragma unroll
    for (int q = 0; q < NC / 4; q++) {
      int i0 = base + q * 4;
      float4 hv = make_float4(hr[q * 4 + 0], hr[q * 4 + 1],
                              hr[q * 4 + 2], hr[q * 4 + 3]);
      float4 rq = make_float4(rv[q * 4 + 0] - hv.x, rv[q * 4 + 1] - hv.y,
                              rv[q * 4 + 2] - hv.z, rv[q * 4 + 3] - hv.w);
      *(float4*)&outk[i0] = hv;
      *(float4*)&res[i0] = rq;
      *(float4*)&h[physi(i0)] = rq;
      hr[q * 4 + 0] = rq.x; hr[q * 4 + 1] = rq.y;
      hr[q * 4 + 2] = rq.z; hr[q * 4 + 3] = rq.w;
    }
    // ---- grid barrier + flatness decision ----
    ep++;
    __syncthreads();
    if (t == 0) {
      __hip_atomic_fetch_add(cnt, 1u, __ATOMIC_ACQ_REL, __HIP_MEMORY_SCOPE_AGENT);
      unsigned tgt = ep * gridDim.x;
      while (__hip_atomic_load(cnt, __ATOMIC_ACQUIRE, __HIP_MEMORY_SCOPE_AGENT) < tgt)
        __builtin_amdgcn_s_sleep(1);
      double S1 = __hip_atomic_load(&flsl[k * 4 + 0], __ATOMIC_RELAXED, __HIP_MEMORY_SCOPE_AGENT);
      double S2 = __hip_atomic_load(&flsl[k * 4 + 1], __ATOMIC_RELAXED, __HIP_MEMORY_SCOPE_AGENT);
      double S3 = __hip_atomic_load(&flsl[k * 4 + 2], __ATOMIC_RELAXED, __HIP_MEMORY_SCOPE_AGENT);
      double S4 = __hip_atomic_load(&flsl[k * 4 + 3], __ATOMIC_RELAXED, __HIP_MEMORY_SCOPE_AGENT);
      double nr = (double)NB * (double)NL;
      double nd = (double)NB * (double)(NL - 1);
      double varr = (S2 - S1 * S1 / nr) / (nr - 1.0);
      double vard = (S4 - S3 * S3 / nd) / (nd - 1.0);
      sFlag = (vard < 0.05 * varr) ? 1 : 0;
    }
    __syncthreads();
    done = done || (sFlag != 0);
  }
}

extern "C" void kernel_launch(void* const* d_in, const int* in_sizes, int n_in,
                              void* d_out, int out_size, void* d_ws, size_t ws_size,
                              hipStream_t stream) {
  const float* x = (const float*)d_in[0];
  float* out = (float*)d_out;
  // ws layout: [0] barrier counter; [256] sd slots (6*12*2 dbl); [1408] flat slots (6*4 dbl)
  size_t zb = ws_size < 4096 ? ws_size : 4096;
  hipMemsetAsync(d_ws, 0, zb, stream);
  unsigned* cnt = (unsigned*)d_ws;
  double* sdsl = (double*)((char*)d_ws + 256);
  double* flsl = (double*)((char*)d_ws + 256 + (size_t)N_IMFS * N_ITER * 2 * 8);
  hipLaunchKernelGGL(emd_main, dim3(NB), dim3(NT), 0, stream, x, out, cnt, sdsl, flsl);
}

// Round 6
// 286.202 us; speedup vs baseline: 1.6106x; 1.5162x over previous
//
#include <hip/hip_runtime.h>

#define NL 16384          // row length
#define NB 64             // rows = blocks
#define NT 1024           // threads per block (16 waves = 4 waves/SIMD)
#define NC (NL / NT)      // 16 elements per thread == bits in the peak mask
#define NW (NT / 64)      // 16 waves
#define N_ITER 12
#define N_IMFS 6

#pragma clang fp contract(off)   // everything unfused EXCEPT the explicit fmaf

#define HSZ (NL + (NL >> 5))   // +1 float per 32: 2-way-max banking (free)
__device__ __forceinline__ int physi(int i) { return i + (i >> 5); }

#define FMAXV 3.402823466e38f

// Frozen bit-exact semantics (certified R9/R11, and R13-R16 value path all
// passed absmax 0.0).
// R13-R16 lesson: this toolchain allocates 64 VGPRs for this kernel no
// matter what (launch_bounds min-waves, waves_per_eu(4,4), hard LDS clamp
// >80KB, ext_vector SSA values -- all inert; ~140-190MB scratch whenever the
// plan needs ~96 live regs). So: fit in 64 VGPRs. h stays in LDS (R1-style,
// proven clean), and the DS savings kept are the ones with no array cost:
//  - scan-diet (proven R13-R16): ballot + 1 shfl per carry instead of four
//    6-step bpermute scans; count scan -> reduce; Mx/Mn behind rare branch.
//  - b128 streaming: pass A/C/flatness read h via ds_read_b128 chunks with
//    2 live float4s (was 16-18 scalar ds_read_b32 each).
//  - double-buffered h: pass C writes h_next = hc - mn inline to the other
//    buffer (same FP op/operands as the old h-=mean => bit-identical);
//    decision flips an offset. Kills the subtract pass (-12 b128) and one
//    __syncthreads per iter. mean never materialized.
__global__ __launch_bounds__(NT, 4) void emd_main(
    const float* __restrict__ x, float* __restrict__ out,
    unsigned* cnt, double* sdsl, double* flsl) {
  __shared__ float hbuf[2 * HSZ];   // 135168 B: double-buffered h
  __shared__ int wLU[NW], wLL[NW], wNU[NW], wNL[NW];
  __shared__ float wMx[NW], wMn[NW];
  __shared__ unsigned wCT[NW];
  __shared__ int eLU[NW], eLL[NW], eNU[NW], eNL[NW];
  __shared__ float eMx[NW], eMn[NW];
  __shared__ unsigned sTot;
  __shared__ double tA[NW], tB[NW], tC[NW], tD[NW];
  __shared__ int sFlag;

  const int t = threadIdx.x;
  const int lane = t & 63;
  const int wv = t >> 6;
  const int row = blockIdx.x;
  const int base = t * NC;
  const float* xr = x + (size_t)row * NL;
  float* res = out + (size_t)N_IMFS * NB * NL + (size_t)row * NL;

  int off = 0;   // current h buffer offset (0 or HSZ), block-uniform

  // init: h = x row (LDS, swizzled); res slab of d_out = x
  #pragma unroll
  for (int q = 0; q < NC / 4; q++) {
    int i0 = base + q * 4;
    float4 v = *(const float4*)&xr[i0];
    *(float4*)&hbuf[physi(i0)] = v;
    *(float4*)&res[i0] = v;
  }
  __syncthreads();

  unsigned ep = 0;
  bool done = false;

  for (int k = 0; k < N_IMFS; k++) {
    float* outk = out + (size_t)k * NB * NL + (size_t)row * NL;
    if (done) {  // globally-uniform skip (no barriers)
      #pragma unroll
      for (int q = 0; q < NC / 4; q++)
        *(float4*)&outk[base + q * 4] = make_float4(0.f, 0.f, 0.f, 0.f);
      continue;
    }

    // ---------------- sifting ----------------
    for (int it = 0; it < N_ITER; it++) {
      float* hcur = hbuf + off;
      float* hnx  = hbuf + (off ^ HSZ);

      // pass A: chunked rolling walk -> peak masks + chunk summaries
      unsigned mU = 0, mL = 0;
      int lmU = -1, lmL = -1, cU = 0, cL = 0;
      float rmx = -FMAXV, rmn = FMAXV;
      {
        float hm = (base > 0) ? hcur[physi(base - 1)] : 0.0f;
        float4 cur = *(const float4*)&hcur[physi(base)];
        #define PKSTEP(J, HC, HP) { int i = base + (J);                     \
          bool in = (i > 0) && (i + 1 < NL);                                \
          if (in && hm < (HC) && (HC) > (HP)) { mU |= 1u << (J); lmU = i; cU++; } \
          if (in && hm > (HC) && (HC) < (HP)) { mL |= 1u << (J); lmL = i; cL++; } \
          rmx = fmaxf(rmx, (HC)); rmn = fminf(rmn, (HC)); hm = (HC); }
        #pragma unroll
        for (int q = 0; q < 4; q++) {
          float4 nxt = cur;
          float n0;
          if (q < 3) { nxt = *(const float4*)&hcur[physi(base + q * 4 + 4)]; n0 = nxt.x; }
          else       { n0 = (base + 16 < NL) ? hcur[physi(base + 16)] : 0.0f; }
          PKSTEP(q * 4 + 0, cur.x, cur.y)
          PKSTEP(q * 4 + 1, cur.y, cur.z)
          PKSTEP(q * 4 + 2, cur.z, cur.w)
          PKSTEP(q * 4 + 3, cur.w, n0)
          cur = nxt;
        }
        #undef PKSTEP
      }
      int fpU = mU ? (base + __ffs(mU) - 1) : NL;   // first own peak
      int fpL = mL ? (base + __ffs(mL) - 1) : NL;
      unsigned long long bUm = __ballot(mU != 0);
      unsigned long long bLm = __ballot(mL != 0);
      // wave summaries: owning lane stores directly (no scans)
      {
        int s;
        s = bUm ? (63 - __clzll((long long)bUm)) : 0;
        if (lane == s) wLU[wv] = bUm ? lmU : -1;
        s = bLm ? (63 - __clzll((long long)bLm)) : 0;
        if (lane == s) wLL[wv] = bLm ? lmL : -1;
        s = bUm ? (__ffsll(bUm) - 1) : 0;
        if (lane == s) wNU[wv] = bUm ? fpU : NL;
        s = bLm ? (__ffsll(bLm) - 1) : 0;
        if (lane == s) wNL[wv] = bLm ? fpL : NL;
      }
      // block peak-count totals (reduce only; same pairwise order as before)
      unsigned ict = ((unsigned)cU << 16) | (unsigned)cL;
      #pragma unroll
      for (int o = 1; o < 64; o <<= 1) {
        unsigned cc = __shfl_down(ict, o, 64);
        if (lane + o < 64) ict += cc;
      }
      if (lane == 0) wCT[wv] = ict;
      __syncthreads();
      if (t == 0) {  // 16-entry serial combine -> exclusive wave carries
        int aLU = -1, aLL = -1; unsigned tt = 0;
        for (int w = 0; w < NW; w++) {
          eLU[w] = aLU; aLU = max(aLU, wLU[w]);
          eLL[w] = aLL; aLL = max(aLL, wLL[w]);
          tt += wCT[w];
        }
        int aNU = NL, aNL = NL;
        for (int w = NW - 1; w >= 0; w--) {
          eNU[w] = aNU; aNU = min(aNU, wNU[w]);
          eNL[w] = aNL; aNL = min(aNL, wNL[w]);
        }
        sTot = tt;
      }
      __syncthreads();
      const unsigned tot = sTot;
      const int totU = (int)(tot >> 16), totL = (int)(tot & 0xffffu);

      // per-thread carries via ballot bit-ops + one dynamic shuffle each
      unsigned long long belowU = bUm & ((1ull << lane) - 1ull);
      unsigned long long belowL = bLm & ((1ull << lane) - 1ull);
      unsigned long long aboveU = (lane == 63) ? 0ull : (bUm & (~0ull << (lane + 1)));
      unsigned long long aboveL = (lane == 63) ? 0ull : (bLm & (~0ull << (lane + 1)));
      int slU = belowU ? (63 - __clzll((long long)belowU)) : 0;
      int slL = belowL ? (63 - __clzll((long long)belowL)) : 0;
      int snU = aboveU ? (__ffsll(aboveU) - 1) : 0;
      int snL = aboveL ? (__ffsll(aboveL) - 1) : 0;
      int gU  = __shfl(lmU, slU, 64);
      int gL  = __shfl(lmL, slL, 64);
      int gNU = __shfl(fpU, snU, 64);
      int gNL = __shfl(fpL, snL, 64);
      const int clU = belowU ? gU  : eLU[wv];
      const int clL = belowL ? gL  : eLL[wv];
      const int cnU = aboveU ? gNU : eNU[wv];
      const int cnL = aboveL ? gNL : eNL[wv];

      // Mx/Mn prefix carries only needed for the <2-peaks fallback (rare);
      // tot is block-uniform so the branch (and its barriers) is uniform.
      float crx = -FMAXV, crn = FMAXV;
      if (totU < 2 || totL < 2) {
        float iMx = rmx, iMn = rmn;
        #pragma unroll
        for (int o = 1; o < 64; o <<= 1) {
          float fa = __shfl_up(iMx, o, 64);
          float fb = __shfl_up(iMn, o, 64);
          if (lane >= o) { iMx = fmaxf(iMx, fa); iMn = fminf(iMn, fb); }
        }
        if (lane == 63) { wMx[wv] = iMx; wMn[wv] = iMn; }
        __syncthreads();
        if (t == 0) {
          float aMx = -FMAXV, aMn = FMAXV;
          for (int w = 0; w < NW; w++) {
            eMx[w] = aMx; aMx = fmaxf(aMx, wMx[w]);
            eMn[w] = aMn; aMn = fminf(aMn, wMn[w]);
          }
        }
        __syncthreads();
        float pMx = __shfl_up(iMx, 1, 64); if (lane == 0) pMx = -FMAXV;
        float pMn = __shfl_up(iMn, 1, 64); if (lane == 0) pMn = FMAXV;
        crx = fmaxf(eMx[wv], pMx);
        crn = fminf(eMn[wv], pMn);
      }

      // pass C: envelopes + mean (frozen f32 ladder), streaming b128 chunks;
      // h_next = hc - mn written inline to the other buffer (dbuf subtract).
      double pm2 = 0.0, ph2 = 0.0;
      {
        float rx = crx, rn = crn;
        int curLU = clU, curLL = clL;
        float vl = hcur[physi(clU < 0 ? 0 : clU)];   // carry-in gathers
        float wl = hcur[physi(clL < 0 ? 0 : clL)];
        int gB = -0x7fffffff, gD = -0x7fffffff;
        float vr = 0.0f, wr = 0.0f;
        #define ENVSTEP(J, HC, OD) { int i = base + (J); float hc = (HC);   \
          rx = fmaxf(rx, hc); rn = fminf(rn, hc);                           \
          if ((mU >> (J)) & 1u) { curLU = i; vl = hc; }                     \
          if ((mL >> (J)) & 1u) { curLL = i; wl = hc; }                     \
          int lU = curLU, lL = curLL;                                       \
          unsigned highm = 0xFFFFFFFFu << (J); unsigned a;                  \
          a = mU & highm; int nUv = a ? (base + __ffs(a) - 1) : cnU;        \
          a = mL & highm; int nLv = a ? (base + __ffs(a) - 1) : cnL;        \
          if (nUv != gB) { gB = nUv; vr = hcur[physi(nUv >= NL ? NL - 1 : nUv)]; } \
          if (nLv != gD) { gD = nLv; wr = hcur[physi(nLv >= NL ? NL - 1 : nLv)]; } \
          int den = nUv - lU;                                               \
          float fracU = (float)(i - lU) / (float)(den > 0 ? den : 1);       \
          float envU = (den > 0) ? __builtin_fmaf(fracU, vr - vl, vl) : vl; \
          if (lU < 0) envU = vr;                                            \
          if (nUv >= NL) envU = vl;                                         \
          if (totU < 2) envU = rx;                                          \
          int den2 = nLv - lL;                                              \
          float fracL = (float)(i - lL) / (float)(den2 > 0 ? den2 : 1);     \
          float envL = (den2 > 0) ? __builtin_fmaf(fracL, wr - wl, wl) : wl;\
          if (lL < 0) envL = wr;                                            \
          if (nLv >= NL) envL = wl;                                         \
          if (totL < 2) envL = rn;                                          \
          float mn = 0.5f * (envU + envL);                                  \
          (OD) = hc - mn;                                                   \
          pm2 += (double)mn * (double)mn; ph2 += (double)hc * (double)hc; }
        #pragma unroll
        for (int q = 0; q < 4; q++) {
          int i0 = base + q * 4;
          float4 hv4 = *(const float4*)&hcur[physi(i0)];
          float4 o4;
          ENVSTEP(q * 4 + 0, hv4.x, o4.x)
          ENVSTEP(q * 4 + 1, hv4.y, o4.y)
          ENVSTEP(q * 4 + 2, hv4.z, o4.z)
          ENVSTEP(q * 4 + 3, hv4.w, o4.w)
          *(float4*)&hnx[physi(i0)] = o4;
        }
        #undef ENVSTEP
      }
      // fused block reduction of (pm2, ph2): wave shuffle, publish, t0 combines
      #pragma unroll
      for (int o = 1; o < 64; o <<= 1) {
        double a = __shfl_down(pm2, o, 64);
        double b = __shfl_down(ph2, o, 64);
        if (lane + o < 64) { pm2 += a; ph2 += b; }
      }
      if (lane == 0) { tA[wv] = pm2; tB[wv] = ph2; }
      // ---- grid barrier + convergence decision ----
      ep++;
      __syncthreads();   // orders tA/tB (and hnx writes) before t0 / reuse
      if (t == 0) {
        double sA = 0.0, sB = 0.0;
        for (int w = 0; w < NW; w++) { sA += tA[w]; sB += tB[w]; }
        atomicAdd(&sdsl[(k * N_ITER + it) * 2 + 0], sA);
        atomicAdd(&sdsl[(k * N_ITER + it) * 2 + 1], sB);
        __hip_atomic_fetch_add(cnt, 1u, __ATOMIC_ACQ_REL, __HIP_MEMORY_SCOPE_AGENT);
        unsigned tgt = ep * gridDim.x;
        while (__hip_atomic_load(cnt, __ATOMIC_ACQUIRE, __HIP_MEMORY_SCOPE_AGENT) < tgt)
          __builtin_amdgcn_s_sleep(1);
        double m2 = __hip_atomic_load(&sdsl[(k * N_ITER + it) * 2 + 0],
                                      __ATOMIC_RELAXED, __HIP_MEMORY_SCOPE_AGENT);
        double h2 = __hip_atomic_load(&sdsl[(k * N_ITER + it) * 2 + 1],
                                      __ATOMIC_RELAXED, __HIP_MEMORY_SCOPE_AGENT);
        sFlag = (m2 / (h2 + 1e-8) < 0.05) ? 1 : 0;
      }
      __syncthreads();
      if (sFlag) break;   // converged: keep OLD buffer (h frozen, JAX latch)
      off ^= HSZ;         // accept h_next: uniform flip, no barrier needed
    }

    // ------------- flatness test + outputs (f32 values, f64 sums) -------------
    float* hcur = hbuf + off;
    double s1 = 0.0, s2 = 0.0, s3 = 0.0, s4 = 0.0;
    {
      float rb = 0.0f;   // res-h at base+NC (next thread's first element)
      if (base + NC < NL) rb = res[base + NC] - hcur[physi(base + NC)];
      float4 rv4 = *(const float4*)&res[base];
      float4 hv4 = *(const float4*)&hcur[physi(base)];
      float e0 = rv4.x - hv4.x, e1 = rv4.y - hv4.y,
            e2 = rv4.z - hv4.z, e3 = rv4.w - hv4.w;
      #define FLSTEP(J, CUR, NXT) { int i = base + (J);                     \
        s1 += (double)(CUR); s2 += (double)(CUR) * (double)(CUR);           \
        if (i + 1 < NL) { float dd = (NXT) - (CUR);                         \
          s3 += (double)dd; s4 += (double)dd * (double)dd; } }
      #pragma unroll
      for (int q = 0; q < 4; q++) {
        float c0 = e0, c1 = e1, c2 = e2, c3 = e3;
        float n0;
        if (q < 3) {
          int i0 = base + q * 4 + 4;
          rv4 = *(const float4*)&res[i0];
          hv4 = *(const float4*)&hcur[physi(i0)];
          e0 = rv4.x - hv4.x; e1 = rv4.y - hv4.y;
          e2 = rv4.z - hv4.z; e3 = rv4.w - hv4.w;
          n0 = e0;
        } else n0 = rb;
        FLSTEP(q * 4 + 0, c0, c1)
        FLSTEP(q * 4 + 1, c1, c2)
        FLSTEP(q * 4 + 2, c2, c3)
        FLSTEP(q * 4 + 3, c3, n0)
      }
      #undef FLSTEP
    }
    #pragma unroll
    for (int o = 1; o < 64; o <<= 1) {
      double a = __shfl_down(s1, o, 64);
      double b = __shfl_down(s2, o, 64);
      double c = __shfl_down(s3, o, 64);
      double d = __shfl_down(s4, o, 64);
      if (lane + o < 64) { s1 += a; s2 += b; s3 += c; s4 += d; }
    }
    if (lane == 0) { tA[wv] = s1; tB[wv] = s2; tC[wv] = s3; tD[wv] = s4; }
    __syncthreads();   // orders publishes AND all cross-thread h/res reads above
    if (t == 0) {
      double S1 = 0.0, S2 = 0.0, S3 = 0.0, S4 = 0.0;
      for (int w = 0; w < NW; w++) { S1 += tA[w]; S2 += tB[w]; S3 += tC[w]; S4 += tD[w]; }
      atomicAdd(&flsl[k * 4 + 0], S1);
      atomicAdd(&flsl[k * 4 + 1], S2);
      atomicAdd(&flsl[k * 4 + 2], S3);
      atomicAdd(&flsl[k * 4 + 3], S4);
    }
    // outputs: IMF k = h; res -= h; h <- new res (current buffer)
    #pragma unroll
    for (int q = 0; q < NC / 4; q++) {
      int i0 = base + q * 4;
      int p0 = physi(i0);
      float4 rv = *(const float4*)&res[i0];
      float4 hv = *(const float4*)&hcur[p0];
      float4 rq = make_float4(rv.x - hv.x, rv.y - hv.y, rv.z - hv.z, rv.w - hv.w);
      *(float4*)&outk[i0] = hv;
      *(float4*)&res[i0] = rq;
      *(float4*)&hcur[p0] = rq;
    }
    // ---- grid barrier + flatness decision ----
    ep++;
    __syncthreads();
    if (t == 0) {
      __hip_atomic_fetch_add(cnt, 1u, __ATOMIC_ACQ_REL, __HIP_MEMORY_SCOPE_AGENT);
      unsigned tgt = ep * gridDim.x;
      while (__hip_atomic_load(cnt, __ATOMIC_ACQUIRE, __HIP_MEMORY_SCOPE_AGENT) < tgt)
        __builtin_amdgcn_s_sleep(1);
      double S1 = __hip_atomic_load(&flsl[k * 4 + 0], __ATOMIC_RELAXED, __HIP_MEMORY_SCOPE_AGENT);
      double S2 = __hip_atomic_load(&flsl[k * 4 + 1], __ATOMIC_RELAXED, __HIP_MEMORY_SCOPE_AGENT);
      double S3 = __hip_atomic_load(&flsl[k * 4 + 2], __ATOMIC_RELAXED, __HIP_MEMORY_SCOPE_AGENT);
      double S4 = __hip_atomic_load(&flsl[k * 4 + 3], __ATOMIC_RELAXED, __HIP_MEMORY_SCOPE_AGENT);
      double nr = (double)NB * (double)NL;
      double nd = (double)NB * (double)(NL - 1);
      double varr = (S2 - S1 * S1 / nr) / (nr - 1.0);
      double vard = (S4 - S3 * S3 / nd) / (nd - 1.0);
      sFlag = (vard < 0.05 * varr) ? 1 : 0;
    }
    __syncthreads();
    done = done || (sFlag != 0);
  }
}

extern "C" void kernel_launch(void* const* d_in, const int* in_sizes, int n_in,
                              void* d_out, int out_size, void* d_ws, size_t ws_size,
                              hipStream_t stream) {
  const float* x = (const float*)d_in[0];
  float* out = (float*)d_out;
  // ws layout: [0] barrier counter; [256] sd slots (6*12*2 dbl); [1408] flat slots (6*4 dbl)
  size_t zb = ws_size < 4096 ? ws_size : 4096;
  hipMemsetAsync(d_ws, 0, zb, stream);
  unsigned* cnt = (unsigned*)d_ws;
  double* sdsl = (double*)((char*)d_ws + 256);
  double* flsl = (double*)((char*)d_ws + 256 + (size_t)N_IMFS * N_ITER * 2 * 8);
  hipLaunchKernelGGL(emd_main, dim3(NB), dim3(NT), 0, stream, x, out, cnt, sdsl, flsl);
}